// Round 2
// baseline (598.342 us; speedup 1.0000x reference)
//
#include <hip/hip_runtime.h>
#include <hip/hip_bf16.h>
#include <stdint.h>

#define NV 300000
#define KOFF 27
#define BM 128

typedef __bf16 bf16x8 __attribute__((ext_vector_type(8)));
typedef float f32x4 __attribute__((ext_vector_type(4)));
typedef unsigned short u16;

__device__ __forceinline__ u16 f2bf(float f) {
  uint32_t u = __float_as_uint(f);
  uint32_t r = (u + 0x7fffu + ((u >> 16) & 1u)) >> 16;
  return (u16)r;
}

__device__ __forceinline__ void async16(const void* g, void* l) {
  __builtin_amdgcn_global_load_lds(
      (const __attribute__((address_space(1))) uint32_t*)g,
      (__attribute__((address_space(3))) uint32_t*)l, 16, 0, 0);
}

// ---- convert x (f32) -> bf16 table ----
__global__ void cvt_x_kernel(const float* __restrict__ x, u16* __restrict__ xb,
                             int n) {
  int i = (blockIdx.x * 256 + threadIdx.x) * 8;
  if (i >= n) return;
  const float4 a = *(const float4*)(x + i);
  const float4 b = *(const float4*)(x + i + 4);
  uint4 o;
  o.x = (uint32_t)f2bf(a.x) | ((uint32_t)f2bf(a.y) << 16);
  o.y = (uint32_t)f2bf(a.z) | ((uint32_t)f2bf(a.w) << 16);
  o.z = (uint32_t)f2bf(b.x) | ((uint32_t)f2bf(b.y) << 16);
  o.w = (uint32_t)f2bf(b.z) | ((uint32_t)f2bf(b.w) << 16);
  *(uint4*)(xb + i) = o;
}

// ---- convert W -> bf16, transposed to [k][co][ci] (linear, no swizzle:
// B-fragments are loaded straight from global now, LDS not involved) ----
__global__ void cvt_w_kernel(const float* __restrict__ W0,
                             const float* __restrict__ W1,
                             u16* __restrict__ W0t, u16* __restrict__ W1t) {
  int t = blockIdx.x * 256 + threadIdx.x;  // 27648 total
  const float* W = W0;
  u16* Wt = W0t;
  if (t >= 13824) { W = W1; Wt = W1t; t -= 13824; }
  const int p = t & 7;
  const int col = (t >> 3) & 63;   // output channel
  const int k = t >> 9;            // 0..26
  u16 h[8];
#pragma unroll
  for (int j = 0; j < 8; j++)
    h[j] = f2bf(W[((size_t)k * 64 + p * 8 + j) * 64 + col]);
  uint4 o;
  o.x = (uint32_t)h[0] | ((uint32_t)h[1] << 16);
  o.y = (uint32_t)h[2] | ((uint32_t)h[3] << 16);
  o.z = (uint32_t)h[4] | ((uint32_t)h[5] << 16);
  o.w = (uint32_t)h[6] | ((uint32_t)h[7] << 16);
  *(uint4*)(Wt + ((size_t)k * 64 + col) * 64 + p * 8) = o;
}

// ---- barrier-free gather-GEMM conv ----
// Each wave owns 32 rows: stages its own A gathers (2-deep pipeline, counted
// vmcnt), loads its own W[k] fragments from global (L2-resident), no
// __syncthreads anywhere. MODE 0: relu -> bf16 mid. MODE 1: +bias+resid -> f32.
template <int MODE>
__global__ __launch_bounds__(256, 4) void conv_kernel(
    const u16* __restrict__ tab,   // [NV][64] bf16
    const u16* __restrict__ Wt,    // [27][64][64] bf16 (B^T, linear)
    const float* __restrict__ bias,
    const int* __restrict__ nbr,   // [27][NV]
    const float* __restrict__ resid, void* __restrict__ outp) {
  __shared__ __align__(16) u16 lsA[2][4][32 * 64];  // 2 bufs x 4 waves x 4KB
  const int t = threadIdx.x;
  const int w = t >> 6;
  const int l = t & 63;
  const int row0 = blockIdx.x * BM + w * 32;  // this wave's first row

  f32x4 acc[2][4] = {};
  float bv[4];
#pragma unroll
  for (int n = 0; n < 4; n++) bv[n] = bias[n * 16 + (l & 15)];

  int idxA[4], idxB[4];

  auto loadIdx = [&](int k, int* dst) {
#pragma unroll
    for (int q = 0; q < 4; q++) {
      const int gr = row0 + q * 8 + (l >> 3);
      dst[q] = (gr < NV) ? nbr[(size_t)k * NV + gr] : 0;
    }
  };

  // stage 32 rows into this wave's private LDS buffer, pre-swizzled source
  auto issueStage = [&](int bi, const int* idx) {
#pragma unroll
    for (int q = 0; q < 4; q++) {
      const int r = q * 8 + (l >> 3);       // row within wave tile
      const int seg = (l & 7) ^ (r & 7);    // pre-swizzled source chunk
      async16(tab + (size_t)idx[q] * 64 + seg * 8,
              (char*)(&lsA[bi][w][0]) + q * 1024);
    }
  };

  bf16x8 bf[4][2];
  auto loadB = [&](int k) {
    const u16* B = Wt + (size_t)k * 4096;
#pragma unroll
    for (int n = 0; n < 4; n++)
#pragma unroll
      for (int kk = 0; kk < 2; kk++) {
        const int col = n * 16 + (l & 15);
        const int c = kk * 4 + (l >> 4);
        bf[n][kk] = *(const bf16x8*)(B + col * 64 + c * 8);
      }
  };

  auto compute = [&](int bi) {
    const u16* A = &lsA[bi][w][0];
    bf16x8 af[2][2];
#pragma unroll
    for (int m = 0; m < 2; m++) {
      const int row = m * 16 + (l & 15);
#pragma unroll
      for (int kk = 0; kk < 2; kk++) {
        const int c = kk * 4 + (l >> 4);
        af[m][kk] = *(const bf16x8*)(A + row * 64 + ((c ^ (row & 7)) * 8));
      }
    }
#pragma unroll
    for (int m = 0; m < 2; m++)
#pragma unroll
      for (int n = 0; n < 4; n++)
#pragma unroll
        for (int kk = 0; kk < 2; kk++)
          acc[m][n] = __builtin_amdgcn_mfma_f32_16x16x32_bf16(
              af[m][kk], bf[n][kk], acc[m][n], 0, 0, 0);
  };

  // prologue
  loadIdx(0, idxA);
  asm volatile("" ::: "memory");
  issueStage(0, idxA);  // compiler inserts the idx wait before addr calc
  asm volatile("" ::: "memory");
  loadIdx(1, idxB);
  asm volatile("" ::: "memory");

#pragma unroll 1
  for (int k = 0; k < KOFF; k++) {
    asm volatile("s_waitcnt lgkmcnt(0)" ::: "memory");  // prior ds_reads done
    loadB(k);                                  // 8 vmem (L2-resident)
    asm volatile("" ::: "memory");
    issueStage((k + 1) & 1, idxB);             // 4 vmem (stage k+1; k=26: dup)
    asm volatile("" ::: "memory");
    loadIdx(k + 2 < KOFF ? k + 2 : KOFF - 1, idxA);  // 4 vmem
    asm volatile("" ::: "memory");
    // drain B(k) + stage(k); leave stage(k+1)+idx in flight (counted, never 0)
    asm volatile("s_waitcnt vmcnt(8)" ::: "memory");
    __builtin_amdgcn_sched_barrier(0);
    compute(k & 1);
#pragma unroll
    for (int q = 0; q < 4; q++) idxB[q] = idxA[q];
  }

  // epilogue: C/D layout col=lane&15, row=(lane>>4)*4+j  [m89]
#pragma unroll
  for (int m = 0; m < 2; m++) {
#pragma unroll
    for (int n = 0; n < 4; n++) {
      const int col = n * 16 + (l & 15);
#pragma unroll
      for (int j = 0; j < 4; j++) {
        const int row = row0 + m * 16 + (l >> 4) * 4 + j;
        if (row < NV) {
          float v = acc[m][n][j] + bv[n];
          if (MODE == 0) {
            ((u16*)outp)[(size_t)row * 64 + col] = f2bf(v < 0.f ? 0.f : v);
          } else {
            ((float*)outp)[(size_t)row * 64 + col] =
                v + resid[(size_t)row * 64 + col];
          }
        }
      }
    }
  }
}

extern "C" void kernel_launch(void* const* d_in, const int* in_sizes, int n_in,
                              void* d_out, int out_size, void* d_ws,
                              size_t ws_size, hipStream_t stream) {
  const float* x = (const float*)d_in[0];
  const float* W0 = (const float*)d_in[1];
  const float* b0 = (const float*)d_in[2];
  const float* W1 = (const float*)d_in[3];
  const float* b1 = (const float*)d_in[4];
  const int* nbr = (const int*)d_in[5];

  // ws layout: xb 38.4MB | midb 38.4MB | W0t 216KB | W1t 216KB
  if (ws_size < 77242368) return;
  char* ws = (char*)d_ws;
  u16* xb = (u16*)(ws);
  u16* midb = (u16*)(ws + 38400000);
  u16* W0t = (u16*)(ws + 76800000);
  u16* W1t = (u16*)(ws + 77021184);

  cvt_w_kernel<<<108, 256, 0, stream>>>(W0, W1, W0t, W1t);
  cvt_x_kernel<<<9375, 256, 0, stream>>>(x, xb, NV * 64);

  const int nblk = (NV + BM - 1) / BM;  // 2344
  conv_kernel<0><<<nblk, 256, 0, stream>>>(xb, W0t, b0, nbr, nullptr, midb);
  conv_kernel<1><<<nblk, 256, 0, stream>>>(midb, W1t, b1, nbr, x, d_out);
}